// Round 8
// baseline (100.613 us; speedup 1.0000x reference)
//
#include <hip/hip_runtime.h>
#include <hip/hip_bf16.h>

#define S_LEN 4096
#define DK    64
#define BQ    64
#define BK    64
#define PSTR  40   // padded P row stride (shorts), 8-short aligned for b128

typedef __bf16 bf16x8  __attribute__((ext_vector_type(8)));
typedef float  f32x16  __attribute__((ext_vector_type(16)));

__device__ __forceinline__ short f2bf(float f) {
    union { __bf16 h; short s; } u; u.h = (__bf16)f; return u.s;
}

// Flash attention, causal, scale=1/64 (folded into Q), pad-mask (s==0 -> -inf).
// 256 blocks x 512 threads; block x handles q-tiles (63-x, x) sequentially.
// 8 waves = 4 key-split groups x 2 q-subtiles(32 rows, 32x32 MFMA).
// Swapped QK^T (mfma(K,Q) -> S^T): lane owns full softmax row (q=lane&31).
// Quad staging (4 tiles/iter), double-buffered, ONE barrier per quad-iter.
// Always 17 quad-iters per block. 4-way f32 merge via retired K-LDS.
__global__ __launch_bounds__(512, 2) void attn_kernel(
    const float* __restrict__ Q, const float* __restrict__ K,
    const float* __restrict__ V, float* __restrict__ O)
{
    __shared__ __align__(16) short Ks[2][4][64 * 64];   // [buf][tile][key][dk] swizzled
    __shared__ __align__(16) short Vts[2][4][64 * 64];  // [buf][tile][dk][key] swizzled
    __shared__ __align__(16) short Pb[8][32 * PSTR];    // per-wave P chunk [q][32k+pad]
    __shared__ float2 Ml[4][2][32];                      // [grp][qsub][qrow] {m,l}

    const int tid  = threadIdx.x;
    const int wave = tid >> 6;
    const int lane = tid & 63;
    const int q32  = lane & 31;
    const int hi   = lane >> 5;
    const int hi4  = hi * 4;
    const int hi8  = hi * 8;
    const int grp  = wave & 3;   // key-split group: computes k-tile 4p+grp
    const int qsub = wave >> 2;  // 32-row q sub-tile

    const int batch = blockIdx.y;
    const size_t bo = (size_t)batch * S_LEN * DK;
    const float* Kb = K + bo;
    const float* Vb = V + bo;

    float4 kreg[8];
    float4 vreg[2][4];

    auto load_quad = [&](int kbase) {
        #pragma unroll
        for (int i = 0; i < 8; ++i) {
            const int idx = tid + 512 * i;           // 0..4095 float4s
            const int r256 = idx >> 4;               // key row within quad
            const int col  = (idx & 15) * 4;
            kreg[i] = *reinterpret_cast<const float4*>(Kb + (size_t)(kbase + r256) * DK + col);
        }
        #pragma unroll
        for (int i = 0; i < 2; ++i) {
            const int b    = tid + 512 * i;          // 4x4 transpose block id
            const int tile = b >> 8;
            const int rb   = (b >> 4) & 15;
            const int cb   = b & 15;
            #pragma unroll
            for (int j = 0; j < 4; ++j)
                vreg[i][j] = *reinterpret_cast<const float4*>(
                    Vb + (size_t)(kbase + tile * 64 + 4 * rb + j) * DK + 4 * cb);
        }
    };

    auto store_quad = [&](int buf) {
        #pragma unroll
        for (int i = 0; i < 8; ++i) {
            const int idx = tid + 512 * i;
            const int r256 = idx >> 4;
            const int col  = (idx & 15) * 4;
            const int tile = r256 >> 6, row = r256 & 63;
            short4 sp;
            sp.x = f2bf(kreg[i].x); sp.y = f2bf(kreg[i].y);
            sp.z = f2bf(kreg[i].z); sp.w = f2bf(kreg[i].w);
            *reinterpret_cast<short4*>(&Ks[buf][tile][row * 64 + (col ^ ((row & 7) << 3))]) = sp;
        }
        #pragma unroll
        for (int i = 0; i < 2; ++i) {
            const int b    = tid + 512 * i;
            const int tile = b >> 8;
            const int rb   = (b >> 4) & 15;
            const int cb   = b & 15;
            #pragma unroll
            for (int jj = 0; jj < 4; ++jj) {
                const int d = 4 * cb + jj;
                const float e0 = (jj == 0) ? vreg[i][0].x : (jj == 1) ? vreg[i][0].y : (jj == 2) ? vreg[i][0].z : vreg[i][0].w;
                const float e1 = (jj == 0) ? vreg[i][1].x : (jj == 1) ? vreg[i][1].y : (jj == 2) ? vreg[i][1].z : vreg[i][1].w;
                const float e2 = (jj == 0) ? vreg[i][2].x : (jj == 1) ? vreg[i][2].y : (jj == 2) ? vreg[i][2].z : vreg[i][2].w;
                const float e3 = (jj == 0) ? vreg[i][3].x : (jj == 1) ? vreg[i][3].y : (jj == 2) ? vreg[i][3].z : vreg[i][3].w;
                short4 sp;
                sp.x = f2bf(e0); sp.y = f2bf(e1); sp.z = f2bf(e2); sp.w = f2bf(e3);
                *reinterpret_cast<short4*>(&Vts[buf][tile][d * 64 + ((4 * rb) ^ ((d & 7) << 3))]) = sp;
            }
        }
    };

    const float NEG_INF = -__builtin_inff();
    const int swzA = (q32 & 7) << 3;  // rows q32 and 32+q32 share the same swizzle

    #pragma unroll 1
    for (int qi = 0; qi < 2; ++qi) {
        const int qb = qi ? (int)blockIdx.x : 63 - (int)blockIdx.x;
        const int q0 = qb * BQ;
        const int ntiles = qb + 1;
        const int nquads = (ntiles + 3) >> 2;
        const int qrow   = q0 + 32 * qsub + q32;  // this lane's softmax row

        // Q fragments (B operand), 1/64 folded: qf[s] holds Q[qrow][16s+8hi+e]
        bf16x8 qf[4];
        {
            const float* Qr = Q + bo + (size_t)qrow * DK;
            #pragma unroll
            for (int s = 0; s < 4; ++s) {
                const float4 a = *reinterpret_cast<const float4*>(Qr + 16 * s + hi8);
                const float4 b = *reinterpret_cast<const float4*>(Qr + 16 * s + hi8 + 4);
                qf[s][0] = (__bf16)(a.x * 0.015625f); qf[s][1] = (__bf16)(a.y * 0.015625f);
                qf[s][2] = (__bf16)(a.z * 0.015625f); qf[s][3] = (__bf16)(a.w * 0.015625f);
                qf[s][4] = (__bf16)(b.x * 0.015625f); qf[s][5] = (__bf16)(b.y * 0.015625f);
                qf[s][6] = (__bf16)(b.z * 0.015625f); qf[s][7] = (__bf16)(b.w * 0.015625f);
            }
        }

        float m_run = NEG_INF, l_run = 0.f;
        f32x16 oa0, oa1;  // O[q=crow(r,hi)][d = 32c + q32]
        #pragma unroll
        for (int r = 0; r < 16; ++r) { oa0[r] = 0.f; oa1[r] = 0.f; }

        load_quad(0);
        store_quad(0);
        __syncthreads();

        for (int p = 0; p < nquads; ++p) {
            const int kt = 4 * p + grp;
            const bool pf = (p + 1 < nquads);
            if (pf) load_quad((p + 1) * 4 * BK);  // latency hides under compute

            if (kt < ntiles) {
                const short* Kt = &Ks[p & 1][grp][0];
                const short* Vt = &Vts[p & 1][grp][0];
                const int k0 = kt * BK;
                const int kmax = (kt == qb) ? qrow : 0x7fffffff;  // causal on diag only

                // ---- S^T = K Q  (lane: q=q32 full row; keys crow(r,hi)+32c)
                f32x16 sa0, sa1;
                #pragma unroll
                for (int r = 0; r < 16; ++r) { sa0[r] = 0.f; sa1[r] = 0.f; }
                #pragma unroll
                for (int s = 0; s < 4; ++s) {
                    const int col = (16 * s + hi8) ^ swzA;
                    const bf16x8 kf0 = *reinterpret_cast<const bf16x8*>(&Kt[q32 * 64 + col]);
                    const bf16x8 kf1 = *reinterpret_cast<const bf16x8*>(&Kt[(32 + q32) * 64 + col]);
                    sa0 = __builtin_amdgcn_mfma_f32_32x32x16_bf16(kf0, qf[s], sa0, 0, 0, 0);
                    sa1 = __builtin_amdgcn_mfma_f32_32x32x16_bf16(kf1, qf[s], sa1, 0, 0, 0);
                }

                // ---- masks + row max (in-lane 32 + one cross-half exchange)
                float mt = NEG_INF;
                const int keybase = k0 + hi4;
                #pragma unroll
                for (int r = 0; r < 16; ++r) {
                    const int kl = (r & 3) + 8 * (r >> 2);
                    float x0 = sa0[r];
                    x0 = (x0 == 0.0f) ? NEG_INF : x0;            // pad mask
                    if (keybase + kl > kmax) x0 = NEG_INF;       // causal
                    sa0[r] = x0; mt = fmaxf(mt, x0);
                    float x1 = sa1[r];
                    x1 = (x1 == 0.0f) ? NEG_INF : x1;
                    if (keybase + kl + 32 > kmax) x1 = NEG_INF;
                    sa1[r] = x1; mt = fmaxf(mt, x1);
                }
                mt = fmaxf(mt, __shfl_xor(mt, 32));

                // ---- online update (T13: skip O rescale when max unchanged)
                const float mnew = fmaxf(m_run, mt);
                const bool nochg = (mnew == m_run);
                if (!__all(nochg)) {
                    const float alpha = __expf(m_run - mnew);  // -inf -> 0
                    m_run = mnew;
                    l_run *= alpha;
                    #pragma unroll
                    for (int r = 0; r < 16; ++r) {
                        const float ar = __shfl(alpha, (r & 3) + 8 * (r >> 2) + hi4);
                        oa0[r] *= ar; oa1[r] *= ar;
                    }
                }

                // ---- exp + row sum
                float ps = 0.f;
                #pragma unroll
                for (int r = 0; r < 16; ++r) {
                    sa0[r] = __expf(sa0[r] - m_run); ps += sa0[r];
                    sa1[r] = __expf(sa1[r] - m_run); ps += sa1[r];
                }
                ps += __shfl_xor(ps, 32);
                l_run += ps;

                // ---- chunk 0: P->LDS (b64, padded) then PV
                short* Pw = &Pb[wave][0];
                #pragma unroll
                for (int g = 0; g < 4; ++g) {
                    short4 pk;
                    pk.x = f2bf(sa0[4 * g]);     pk.y = f2bf(sa0[4 * g + 1]);
                    pk.z = f2bf(sa0[4 * g + 2]); pk.w = f2bf(sa0[4 * g + 3]);
                    *reinterpret_cast<short4*>(&Pw[q32 * PSTR + 8 * g + hi4]) = pk;
                }
                #pragma unroll
                for (int s2 = 0; s2 < 2; ++s2) {
                    const bf16x8 pa = *reinterpret_cast<const bf16x8*>(&Pw[q32 * PSTR + 16 * s2 + hi8]);
                    const int vcol = (16 * s2 + hi8) ^ swzA;
                    const bf16x8 vf0 = *reinterpret_cast<const bf16x8*>(&Vt[q32 * 64 + vcol]);
                    const bf16x8 vf1 = *reinterpret_cast<const bf16x8*>(&Vt[(32 + q32) * 64 + vcol]);
                    oa0 = __builtin_amdgcn_mfma_f32_32x32x16_bf16(pa, vf0, oa0, 0, 0, 0);
                    oa1 = __builtin_amdgcn_mfma_f32_32x32x16_bf16(pa, vf1, oa1, 0, 0, 0);
                }
                // ---- chunk 1 (keys +32): reuse P buffer (wave-local DS is in-order)
                #pragma unroll
                for (int g = 0; g < 4; ++g) {
                    short4 pk;
                    pk.x = f2bf(sa1[4 * g]);     pk.y = f2bf(sa1[4 * g + 1]);
                    pk.z = f2bf(sa1[4 * g + 2]); pk.w = f2bf(sa1[4 * g + 3]);
                    *reinterpret_cast<short4*>(&Pw[q32 * PSTR + 8 * g + hi4]) = pk;
                }
                #pragma unroll
                for (int s2 = 0; s2 < 2; ++s2) {
                    const bf16x8 pa = *reinterpret_cast<const bf16x8*>(&Pw[q32 * PSTR + 16 * s2 + hi8]);
                    const int vcol = (32 + 16 * s2 + hi8) ^ swzA;
                    const bf16x8 vf0 = *reinterpret_cast<const bf16x8*>(&Vt[q32 * 64 + vcol]);
                    const bf16x8 vf1 = *reinterpret_cast<const bf16x8*>(&Vt[(32 + q32) * 64 + vcol]);
                    oa0 = __builtin_amdgcn_mfma_f32_32x32x16_bf16(pa, vf0, oa0, 0, 0, 0);
                    oa1 = __builtin_amdgcn_mfma_f32_32x32x16_bf16(pa, vf1, oa1, 0, 0, 0);
                }
            }

            if (pf) store_quad((p + 1) & 1);  // buffer all waves left at iter p-1
            __syncthreads();
        }

        // ---- 4-way merge: m,l via Ml; O (f32) via retired K-LDS
        if (hi == 0) Ml[grp][qsub][q32] = make_float2(m_run, l_run);
        float4* Om4 = reinterpret_cast<float4*>(&Ks[0][0][0]);  // 48KB of 64KB
        if (grp != 0) {
            const int midx = (grp - 1) * 2 + qsub;
            #pragma unroll
            for (int c = 0; c < 2; ++c)
                #pragma unroll
                for (int rq = 0; rq < 4; ++rq) {
                    float4 ov;
                    if (c == 0) { ov.x = oa0[4*rq]; ov.y = oa0[4*rq+1]; ov.z = oa0[4*rq+2]; ov.w = oa0[4*rq+3]; }
                    else        { ov.x = oa1[4*rq]; ov.y = oa1[4*rq+1]; ov.z = oa1[4*rq+2]; ov.w = oa1[4*rq+3]; }
                    Om4[(midx * 8 + c * 4 + rq) * 64 + lane] = ov;
                }
        }
        __syncthreads();
        if (grp == 0) {
            const float* Omf = reinterpret_cast<const float*>(&Ks[0][0][0]);
            float* Ob = O + bo;
            #pragma unroll
            for (int r = 0; r < 16; ++r) {
                const int row_r = (r & 3) + 8 * (r >> 2) + hi4;
                float mg[4], lg[4];
                #pragma unroll
                for (int g = 0; g < 4; ++g) {
                    const float2 v = Ml[g][qsub][row_r];
                    mg[g] = v.x; lg[g] = v.y;
                }
                const float mtot = fmaxf(fmaxf(mg[0], mg[1]), fmaxf(mg[2], mg[3]));
                float eg[4], ltot = 0.f;
                #pragma unroll
                for (int g = 0; g < 4; ++g) {
                    eg[g] = (mg[g] == NEG_INF) ? 0.f : __expf(mg[g] - mtot);
                    ltot += eg[g] * lg[g];
                }
                const float inv = (ltot > 0.f) ? (1.0f / ltot) : 0.f;
                #pragma unroll
                for (int c = 0; c < 2; ++c) {
                    float acc = eg[0] * ((c == 0) ? oa0[r] : oa1[r]);
                    #pragma unroll
                    for (int g = 1; g < 4; ++g) {
                        const int midx = (g - 1) * 2 + qsub;
                        acc += eg[g] * Omf[((midx * 8 + c * 4 + (r >> 2)) * 64 + lane) * 4 + (r & 3)];
                    }
                    Ob[(size_t)(q0 + 32 * qsub + row_r) * DK + 32 * c + q32] = acc * inv;
                }
            }
        }
        __syncthreads();  // protect Ks/Ml before next q-tile restages
    }
}

extern "C" void kernel_launch(void* const* d_in, const int* in_sizes, int n_in,
                              void* d_out, int out_size, void* d_ws, size_t ws_size,
                              hipStream_t stream) {
    (void)in_sizes; (void)n_in; (void)d_ws; (void)ws_size; (void)out_size;
    const float* q = (const float*)d_in[0];
    const float* k = (const float*)d_in[1];
    const float* v = (const float*)d_in[2];
    float* o = (float*)d_out;
    dim3 grid(32, 8);
    dim3 block(512);
    hipLaunchKernelGGL(attn_kernel, grid, block, 0, stream, q, k, v, o);
}